// Round 8
// baseline (53.660 us; speedup 1.0000x reference)
//
#include <hip/hip_runtime.h>
#include <math.h>

// Problem constants: B=8, C=128, H=W=128, HEADS=8
#define N_     16384          // H*W
#define N4     4096           // N_/4 (float4 units per row)
#define BHN    64             // B*HEADS
#define CH     16             // channels per head (hk == hv)
#define CHUNKS 32             // col chunks for k_ctx (512 cols each)

// ws layout (in floats):
//   part[64*32*256] : unnormalized partial context per (bh, chunk)
//   zp  [64*32*16]  : unnormalized partial row-sums per (bh, chunk, kk)
#define WS_PART 0
#define WS_ZP   (BHN * CHUNKS * 256)
// total = 524288 + 32768 floats = 2.23 MB of d_ws (round-5 proven size)

typedef __attribute__((ext_vector_type(8))) short short8;   // 8 x bf16
typedef __attribute__((ext_vector_type(4))) float f32x4;

static __device__ __forceinline__ short f2bf(float f) {
    __bf16 b = (__bf16)f;                      // v_cvt f32->bf16 (RNE)
    return __builtin_bit_cast(short, b);
}

// global -> LDS direct DMA, 16 B per lane. LDS dest = uniform base + lane*16.
static __device__ __forceinline__ void gload16(const float* g, float* l) {
    __builtin_amdgcn_global_load_lds(
        (const __attribute__((address_space(1))) unsigned int*)g,
        (__attribute__((address_space(3))) unsigned int*)l, 16, 0, 0);
}

// ---------------------------------------------------------------- kernel B
// ctx[kk][vv] = sum_n exp(k[kk,n]) * v[vv,n]  via bf16 MFMA.
// Block (chunk,bh): 512-col strip = 4 tiles of 16x128 fp32.
// ALL 16 global_load_lds per wave are issued UP FRONT (64 KB/block in
// flight, zero VGPR) -- then 4 compute phases gated by COUNTED vmcnt
// (12/8/4/0) + raw s_barrier: outstanding loads never drain until the
// last phase. This removes the per-tile load round-trip that kept rounds
// 4-7 latency-bound at ~45us with every pipe <20% busy.
// Swizzle (both-sides, rule 21): phys 16B-unit p of row r holds logical
// unit p^(r&7) (inverse-swizzled GLOBAL source; LDS written linearly by
// HW). Fragment ds_read at phys (v0^(row&7)) -> 8 distinct units mod 8
// across rows -> conflict-free (fixes round-7's even-only key, 2.85M).
// Compute: wave w owns K-step w of each tile (units w*8..w*8+7) -> wave
// partials cover disjoint K-slices; cross-wave sum in cred.
// exp at fragment read (once per element); Z in fp32 before bf16 -> exact.
__global__ __launch_bounds__(256, 2) void k_ctx_mfma(const float* __restrict__ x1,
                                                     const float* __restrict__ x2,
                                                     float* __restrict__ ws) {
    int chunk = blockIdx.x;   // 0..31
    int bh    = blockIdx.y;   // 0..63
    int tid   = threadIdx.x;
    int w = tid >> 6, l = tid & 63;

    __shared__ float ka_s[4][2048];   // 4 x2 tiles (swizzled content)
    __shared__ float va_s[4][2048];   // 4 x1 tiles
    __shared__ float cred[4][256];
    __shared__ float zred[4][16];

    // ---- staging source pointers (per lane; inverse swizzle baked in)
    int half = l >> 5;                    // which of the 2 rows per instr
    int u    = l & 31;                    // physical 16B unit within row
    int rowA = 4 * w + half;              // instr pair A covers rows 4w,4w+1
    int rowB = 4 * w + 2 + half;          // instr pair B covers rows 4w+2,4w+3
    int vA = u ^ (rowA & 7);              // logical 16B unit to fetch
    int vB = u ^ (rowB & 7);
    const float* gk0 = x2 + (size_t)(bh * CH + rowA) * N_ + chunk * 512 + vA * 4;
    const float* gk1 = x2 + (size_t)(bh * CH + rowB) * N_ + chunk * 512 + vB * 4;
    const float* gv0 = x1 + (size_t)(bh * CH + rowA) * N_ + chunk * 512 + vA * 4;
    const float* gv1 = x1 + (size_t)(bh * CH + rowB) * N_ + chunk * 512 + vB * 4;

    // issue ALL 16 loads, tile-major (vmcnt counts retire oldest-first)
    #pragma unroll
    for (int t = 0; t < 4; ++t) {
        gload16(gk0 + t * 128, &ka_s[t][(2 * w)     * 256]);
        gload16(gk1 + t * 128, &ka_s[t][(2 * w + 1) * 256]);
        gload16(gv0 + t * 128, &va_s[t][(2 * w)     * 256]);
        gload16(gv1 + t * 128, &va_s[t][(2 * w + 1) * 256]);
    }

    // ---- compute-side fragment offsets (constant across tiles)
    int row = l & 15;                     // kk for A, vv for B
    int key = row & 7;
    int v0  = w * 8 + (l >> 4) * 2;       // logical 16B unit of fragment
    int off0 = (row * 32 + ((v0    ) ^ key)) * 4;   // float index into tile
    int off1 = (row * 32 + ((v0 + 1) ^ key)) * 4;

    f32x4 acc = {0.f, 0.f, 0.f, 0.f};
    float zacc = 0.f;

#define PHASE(T, VMS)                                                          \
    {                                                                          \
        asm volatile("s_waitcnt vmcnt(" VMS ")" ::: "memory");                 \
        __builtin_amdgcn_s_barrier();                                          \
        __builtin_amdgcn_sched_barrier(0);                                     \
        float4 kq0 = *(const float4*)&ka_s[T][off0];                           \
        float4 kq1 = *(const float4*)&ka_s[T][off1];                           \
        float4 vq0 = *(const float4*)&va_s[T][off0];                           \
        float4 vq1 = *(const float4*)&va_s[T][off1];                           \
        float e0 = __expf(kq0.x), e1 = __expf(kq0.y),                          \
              e2 = __expf(kq0.z), e3 = __expf(kq0.w);                          \
        float e4 = __expf(kq1.x), e5 = __expf(kq1.y),                          \
              e6 = __expf(kq1.z), e7 = __expf(kq1.w);                          \
        zacc += ((e0 + e1) + (e2 + e3)) + ((e4 + e5) + (e6 + e7));             \
        short8 af = {f2bf(e0), f2bf(e1), f2bf(e2), f2bf(e3),                   \
                     f2bf(e4), f2bf(e5), f2bf(e6), f2bf(e7)};                  \
        short8 bv = {f2bf(vq0.x), f2bf(vq0.y), f2bf(vq0.z), f2bf(vq0.w),       \
                     f2bf(vq1.x), f2bf(vq1.y), f2bf(vq1.z), f2bf(vq1.w)};      \
        acc = __builtin_amdgcn_mfma_f32_16x16x32_bf16(af, bv, acc, 0, 0, 0);   \
    }

    PHASE(0, "12")   // tile 0 landed; tiles 1-3 still in flight
    PHASE(1, "8")
    PHASE(2, "4")
    PHASE(3, "0")
#undef PHASE

    // ---- Z reduce: lanes l, l^16, l^32, l^48 cover disjoint col-slices of row l&15
    zacc += __shfl_xor(zacc, 16);
    zacc += __shfl_xor(zacc, 32);
    if (l < 16) zred[w][l] = zacc;

    // ---- ctx reduce: 4 wave partials over disjoint K-slices
    // D layout (m89-verified): lane l, reg r -> ctx[(l>>4)*4 + r][l&15]
    #pragma unroll
    for (int r = 0; r < 4; ++r)
        cred[w][((l >> 4) * 4 + r) * 16 + row] = acc[r];
    __syncthreads();

    if (tid < 16) {
        float zz = (zred[0][tid] + zred[1][tid]) + (zred[2][tid] + zred[3][tid]);
        ws[WS_ZP + (bh * CHUNKS + chunk) * 16 + tid] = zz;
    }
    float c = (cred[0][tid] + cred[1][tid]) + (cred[2][tid] + cred[3][tid]);
    ws[WS_PART + (size_t)(bh * CHUNKS + chunk) * 256 + tid] = c;   // [kk*16+vv]
}

// ---------------------------------------------------------------- kernel C
// Per (bh, 256-col block):
//   prologue: reduce 32 chunk-partials -> ctx[kk][vv] (normalized by Z[kk])
//   phase A : channel softmax of x2 columns (16 channels)
//   phase B : out[vv][n] = sum_kk ctx[kk][vv] * qsm[kk][n]
__global__ __launch_bounds__(256) void k_attend(const float* __restrict__ x2,
                                                const float* __restrict__ ws,
                                                float* __restrict__ out) {
    int cb  = blockIdx.x;   // 0..63 column block (256 cols)
    int bh  = blockIdx.y;   // 0..63
    int tid = threadIdx.x;

    __shared__ float q_s[16][256];   // k tile, then (in-place) qsm tile
    __shared__ float ctxs[256];
    __shared__ float rzs[16];

    // reduce partial context (L2/L3 hits; overlaps with tile load)
    float csum = 0.f;
    #pragma unroll
    for (int c = 0; c < CHUNKS; ++c)
        csum += ws[WS_PART + (size_t)(bh * CHUNKS + c) * 256 + tid];
    if (tid < 16) {
        float z = 0.f;
        #pragma unroll
        for (int c = 0; c < CHUNKS; ++c)
            z += ws[WS_ZP + (bh * CHUNKS + c) * 16 + tid];
        rzs[tid] = 1.0f / z;
    }

    const float4* px = (const float4*)(x2 + (size_t)bh * CH * N_);
    int base4 = cb * 64;             // 256 cols = 64 float4 per row
    #pragma unroll
    for (int r = 0; r < 4; ++r) {
        int idx = r * 256 + tid;
        int ch = idx >> 6, j = idx & 63;
        float4 v = px[(size_t)ch * N4 + base4 + j];
        *(float4*)&q_s[ch][j * 4] = v;
    }
    __syncthreads();

    ctxs[tid] = csum * rzs[tid >> 4];   // ctx[kk][vv], kk = tid>>4

    // phase A: thread = column; softmax over 16 channels, in place
    {
        int col = tid;
        float kv[16];
        #pragma unroll
        for (int c = 0; c < 16; ++c) kv[c] = q_s[c][col];
        float mx = kv[0];
        #pragma unroll
        for (int c = 1; c < 16; ++c) mx = fmaxf(mx, kv[c]);
        float s = 0.f;
        #pragma unroll
        for (int c = 0; c < 16; ++c) { kv[c] = __expf(kv[c] - mx); s += kv[c]; }
        float rs = 1.0f / s;
        #pragma unroll
        for (int c = 0; c < 16; ++c) q_s[c][col] = kv[c] * rs;
    }
    __syncthreads();

    // phase B: thread = (vg, cq); 4 vv x 4 cols register block
    int vg = tid >> 6, cq = tid & 63;
    int vv0 = vg * 4, c0 = cq * 4;
    float4 a0 = make_float4(0.f,0.f,0.f,0.f);
    float4 a1 = a0, a2 = a0, a3 = a0;   // a{c}[v]: col c, 4 vv's
    #pragma unroll
    for (int kk = 0; kk < 16; ++kk) {
        float4 cx = *(const float4*)&ctxs[kk * 16 + vv0];   // wave-uniform -> broadcast
        float4 q4 = *(const float4*)&q_s[kk][c0];
        a0.x = fmaf(q4.x, cx.x, a0.x); a0.y = fmaf(q4.x, cx.y, a0.y);
        a0.z = fmaf(q4.x, cx.z, a0.z); a0.w = fmaf(q4.x, cx.w, a0.w);
        a1.x = fmaf(q4.y, cx.x, a1.x); a1.y = fmaf(q4.y, cx.y, a1.y);
        a1.z = fmaf(q4.y, cx.z, a1.z); a1.w = fmaf(q4.y, cx.w, a1.w);
        a2.x = fmaf(q4.z, cx.x, a2.x); a2.y = fmaf(q4.z, cx.y, a2.y);
        a2.z = fmaf(q4.z, cx.z, a2.z); a2.w = fmaf(q4.z, cx.w, a2.w);
        a3.x = fmaf(q4.w, cx.x, a3.x); a3.y = fmaf(q4.w, cx.y, a3.y);
        a3.z = fmaf(q4.w, cx.z, a3.z); a3.w = fmaf(q4.w, cx.w, a3.w);
    }
    size_t outbase = (size_t)bh * CH * N_ + (size_t)cb * 256 + c0;
    float4 o;
    o = make_float4(a0.x, a1.x, a2.x, a3.x);
    *(float4*)&out[outbase + (size_t)(vv0 + 0) * N_] = o;
    o = make_float4(a0.y, a1.y, a2.y, a3.y);
    *(float4*)&out[outbase + (size_t)(vv0 + 1) * N_] = o;
    o = make_float4(a0.z, a1.z, a2.z, a3.z);
    *(float4*)&out[outbase + (size_t)(vv0 + 2) * N_] = o;
    o = make_float4(a0.w, a1.w, a2.w, a3.w);
    *(float4*)&out[outbase + (size_t)(vv0 + 3) * N_] = o;
}

// ---------------------------------------------------------------- launch
extern "C" void kernel_launch(void* const* d_in, const int* in_sizes, int n_in,
                              void* d_out, int out_size, void* d_ws, size_t ws_size,
                              hipStream_t stream) {
    const float* x1 = (const float*)d_in[0];   // values
    const float* x2 = (const float*)d_in[1];   // keys / queries
    float* out = (float*)d_out;
    float* ws  = (float*)d_ws;

    k_ctx_mfma <<<dim3(CHUNKS, BHN), 256, 0, stream>>>(x1, x2, ws);
    k_attend   <<<dim3(64, BHN),     256, 0, stream>>>(x2, ws, out);
}